// Round 3
// baseline (31856.174 us; speedup 1.0000x reference)
//
#include <hip/hip_runtime.h>
#include <hip/hip_bf16.h>

typedef __hip_bfloat16 bf16;

#define N_NODES 50000
#define N_EDGES 800000
#define DIM 128
#define NH 8
#define HDIM 16

__device__ __forceinline__ float toF(float x){ return x; }
__device__ __forceinline__ float toF(bf16 x){ return __bfloat162float(x); }
__device__ __forceinline__ void storeO(float* p, float v){ *p = v; }
__device__ __forceinline__ void storeO(bf16* p, float v){ *p = __float2bfloat16(v); }

// order-preserving float->uint encoding for atomicMax-based segment max
__device__ __forceinline__ unsigned fenc(float f){
  unsigned u = __float_as_uint(f);
  return (u & 0x80000000u) ? ~u : (u | 0x80000000u);
}
__device__ __forceinline__ float fdec(unsigned u){
  return (u & 0x80000000u) ? __uint_as_float(u ^ 0x80000000u) : __uint_as_float(~u);
}

__global__ void fill_kernel(unsigned* __restrict__ p, unsigned val, int n){
  int i = blockIdx.x * blockDim.x + threadIdx.x;
  if (i < n) p[i] = val;
}

__global__ void copyf_kernel(const float* __restrict__ in, float* __restrict__ out, int n){
  int i = blockIdx.x * blockDim.x + threadIdx.x;
  if (i < n) out[i] = in[i];
}

// LayerNorm over rows of 128; one wave (64 lanes) per row, 4 rows per block.
__global__ __launch_bounds__(256) void ln_kernel(const float* __restrict__ in,
    const float* __restrict__ g, const float* __restrict__ b,
    float* __restrict__ out, int n){
  int row = blockIdx.x * 4 + (threadIdx.x >> 6);
  int lane = threadIdx.x & 63;
  if (row >= n) return;
  const float* p = in + (size_t)row * DIM;
  float a0 = p[lane], a1 = p[lane + 64];
  float s = a0 + a1;
  #pragma unroll
  for (int o = 32; o > 0; o >>= 1) s += __shfl_xor(s, o);
  float mu = s * (1.f / 128.f);
  float d0 = a0 - mu, d1 = a1 - mu;
  float vs = d0 * d0 + d1 * d1;
  #pragma unroll
  for (int o = 32; o > 0; o >>= 1) vs += __shfl_xor(vs, o);
  float rs = rsqrtf(vs * (1.f / 128.f) + 1e-5f);
  out[(size_t)row * DIM + lane]      = d0 * rs * g[lane]      + b[lane];
  out[(size_t)row * DIM + lane + 64] = d1 * rs * g[lane + 64] + b[lane + 64];
}

// Generic tiled GEMM: out[n,M] = act(A[n,K] @ W[K,M] + bias) (+ resid)
// BM=BN=64, BK=32, 256 threads, 4x4 outputs/thread, fp32 accumulate.
template<typename AT, typename OT, bool RELU, bool RESID>
__global__ __launch_bounds__(256) void gemm_kernel(const AT* __restrict__ A,
    const float* __restrict__ W, const float* __restrict__ bias,
    const float* __restrict__ resid, OT* __restrict__ out,
    int n, int K, int M){
  __shared__ float As[32][65];
  __shared__ float Bs[32][65];
  int bm = blockIdx.x * 64;
  int bn = blockIdx.y * 64;
  int tid = threadIdx.x;
  int tx = tid & 15, ty = tid >> 4;
  float acc[4][4] = {{0.f}};
  for (int k0 = 0; k0 < K; k0 += 32){
    int ca = tid & 31, ra = tid >> 5;        // A tile: 64 rows x 32 k
    #pragma unroll
    for (int rr = 0; rr < 8; rr++){
      int r = ra + rr * 8;
      int gr = bm + r;
      float val = 0.f;
      if (gr < n) val = toF(A[(size_t)gr * K + k0 + ca]);
      As[ca][r] = val;
    }
    int cb = tid & 63, rb = tid >> 6;        // W tile: 32 k x 64 cols
    #pragma unroll
    for (int rr = 0; rr < 8; rr++){
      int r = rb + rr * 4;
      int gc = bn + cb;
      float val = 0.f;
      if (gc < M) val = W[(size_t)(k0 + r) * M + gc];
      Bs[r][cb] = val;
    }
    __syncthreads();
    #pragma unroll
    for (int kk = 0; kk < 32; kk++){
      float av[4], bv[4];
      #pragma unroll
      for (int i = 0; i < 4; i++) av[i] = As[kk][ty * 4 + i];
      #pragma unroll
      for (int j = 0; j < 4; j++) bv[j] = Bs[kk][tx * 4 + j];
      #pragma unroll
      for (int i = 0; i < 4; i++)
        #pragma unroll
        for (int j = 0; j < 4; j++) acc[i][j] += av[i] * bv[j];
    }
    __syncthreads();
  }
  #pragma unroll
  for (int i = 0; i < 4; i++){
    int gr = bm + ty * 4 + i;
    if (gr >= n) continue;
    #pragma unroll
    for (int j = 0; j < 4; j++){
      int gc = bn + tx * 4 + j;
      if (gc >= M) continue;
      float v = acc[i][j] + bias[gc];
      if (RELU) v = fmaxf(v, 0.f);
      if (RESID) v += resid[(size_t)gr * M + gc];
      storeO(out + (size_t)gr * M + gc, v);
    }
  }
}

__device__ __forceinline__ float edge_dot(const bf16* __restrict__ q,
    const bf16* __restrict__ k, int s, int d, int h){
  const bf16* qp = q + (size_t)s * DIM + h * HDIM;
  const bf16* kp = k + (size_t)d * DIM + h * HDIM;
  float acc = 0.f;
  #pragma unroll
  for (int i = 0; i < HDIM; i++) acc += toF(qp[i]) * toF(kp[i]);
  return acc * 0.25f;  // 1/sqrt(16)
}

// pass 1: segment max of scores into m_enc[dst,h]
__global__ __launch_bounds__(256) void edge_pass1(const int* __restrict__ src,
    const int* __restrict__ dst, const bf16* __restrict__ q, const bf16* __restrict__ k,
    unsigned* __restrict__ m_enc, int E){
  int t = blockIdx.x * blockDim.x + threadIdx.x;
  if (t >= E * NH) return;
  int e = t >> 3, h = t & 7;
  float sc = edge_dot(q, k, src[e], dst[e], h);
  atomicMax(m_enc + (size_t)dst[e] * NH + h, fenc(sc));
}

// pass 2: denom[dst,h] += exp(score - m)
__global__ __launch_bounds__(256) void edge_pass2(const int* __restrict__ src,
    const int* __restrict__ dst, const bf16* __restrict__ q, const bf16* __restrict__ k,
    const unsigned* __restrict__ m_enc, float* __restrict__ denom, int E){
  int t = blockIdx.x * blockDim.x + threadIdx.x;
  if (t >= E * NH) return;
  int e = t >> 3, h = t & 7;
  int d = dst[e];
  float sc = edge_dot(q, k, src[e], d, h);
  float ex = __expf(sc - fdec(m_enc[(size_t)d * NH + h]));
  atomicAdd(denom + (size_t)d * NH + h, ex);
}

// pass 3: agg[dst, h*16 + i] += v[src, h*16 + i] * ex / denom
__global__ __launch_bounds__(256) void edge_pass3(const int* __restrict__ src,
    const int* __restrict__ dst, const bf16* __restrict__ q, const bf16* __restrict__ k,
    const bf16* __restrict__ v, const unsigned* __restrict__ m_enc,
    const float* __restrict__ denom, float* __restrict__ agg, int E){
  int t = blockIdx.x * blockDim.x + threadIdx.x;
  if (t >= E * NH) return;
  int e = t >> 3, h = t & 7;
  int s = src[e], d = dst[e];
  float sc = edge_dot(q, k, s, d, h);
  float ex = __expf(sc - fdec(m_enc[(size_t)d * NH + h]));
  float p = ex / denom[(size_t)d * NH + h];
  const bf16* vp = v + (size_t)s * DIM + h * HDIM;
  float* ap = agg + (size_t)d * DIM + h * HDIM;
  #pragma unroll
  for (int i = 0; i < HDIM; i++) atomicAdd(ap + i, toF(vp[i]) * p);
}

extern "C" void kernel_launch(void* const* d_in, const int* in_sizes, int n_in,
                              void* d_out, int out_size, void* d_ws, size_t ws_size,
                              hipStream_t stream) {
  const float* x    = (const float*)d_in[0];
  const int*  esrc  = (const int*)d_in[1];
  const int*  edst  = (const int*)d_in[2];
  const float* Wi   = (const float*)d_in[3];
  const float* bi   = (const float*)d_in[4];
  const float* Wq   = (const float*)d_in[5];
  const float* bq   = (const float*)d_in[6];
  const float* Wk   = (const float*)d_in[7];
  const float* bk   = (const float*)d_in[8];
  const float* Wv   = (const float*)d_in[9];
  const float* bv   = (const float*)d_in[10];
  const float* Wo   = (const float*)d_in[11];
  const float* bo   = (const float*)d_in[12];
  const float* g1   = (const float*)d_in[13];
  const float* b1   = (const float*)d_in[14];
  const float* Wf1  = (const float*)d_in[15];
  const float* bf1  = (const float*)d_in[16];
  const float* Wf2  = (const float*)d_in[17];
  const float* bf2  = (const float*)d_in[18];
  const float* gout = (const float*)d_in[19];
  const float* bout_ln = (const float*)d_in[20];
  const float* Wout = (const float*)d_in[21];
  const float* bout = (const float*)d_in[22];

  // workspace: h(ND f32) | r(ND f32) | S(2*ND f32 scratch) = 25.6M floats = 102.4MB
  const size_t ND = (size_t)N_NODES * DIM;         // 6.4M
  float* ws = (float*)d_ws;
  float* h = ws;
  float* r = ws + ND;          // LN output / attention agg (reused)
  float* S = ws + 2 * ND;      // 12.8M floats
  // attention-phase overlay of S:
  bf16* qb = (bf16*)S;         // ND bf16
  bf16* kb = qb + ND;
  bf16* vb = kb + ND;
  unsigned* menc = (unsigned*)(vb + ND);           // N*NH
  float* denom = (float*)(menc + (size_t)N_NODES * NH);
  // FFN-phase overlay of S:
  float* ffnmid = S;           // 2*ND floats

  dim3 B(256);
  dim3 G128(782, 2);   // 50000/64 rows x 128/64 cols
  dim3 G256(782, 4);
  dim3 G40(782, 1);
  const int EH = N_EDGES * NH;     // 6.4M
  const int NHn = N_NODES * NH;    // 400k
  const int EHB = (EH + 255) / 256;

  // h = relu(x @ Wi + bi)
  gemm_kernel<float, float, true, false><<<G128, B, 0, stream>>>(
      x, Wi, bi, nullptr, h, N_NODES, 256, 128);

  for (int l = 0; l < 5; l++){
    const float* Wq_l = Wq + (size_t)l * DIM * DIM;
    const float* Wk_l = Wk + (size_t)l * DIM * DIM;
    const float* Wv_l = Wv + (size_t)l * DIM * DIM;
    const float* Wo_l = Wo + (size_t)l * DIM * DIM;
    const float* Wf1_l = Wf1 + (size_t)l * DIM * 2 * DIM;
    const float* Wf2_l = Wf2 + (size_t)l * 2 * DIM * DIM;

    // r = LN(h)
    ln_kernel<<<12500, B, 0, stream>>>(h, g1 + l * DIM, b1 + l * DIM, r, N_NODES);
    // q/k/v projections (bf16 outputs)
    gemm_kernel<float, bf16, false, false><<<G128, B, 0, stream>>>(
        r, Wq_l, bq + l * DIM, nullptr, qb, N_NODES, 128, 128);
    gemm_kernel<float, bf16, false, false><<<G128, B, 0, stream>>>(
        r, Wk_l, bk + l * DIM, nullptr, kb, N_NODES, 128, 128);
    gemm_kernel<float, bf16, false, false><<<G128, B, 0, stream>>>(
        r, Wv_l, bv + l * DIM, nullptr, vb, N_NODES, 128, 128);
    // zero segment-max/denom/agg (r is free now; reused as agg)
    fill_kernel<<<(NHn + 255) / 256, B, 0, stream>>>(menc, 0u, NHn);
    fill_kernel<<<(NHn + 255) / 256, B, 0, stream>>>((unsigned*)denom, 0u, NHn);
    fill_kernel<<<(int)((ND + 255) / 256), B, 0, stream>>>((unsigned*)r, 0u, (int)ND);
    // edge softmax + aggregation (scores recomputed per pass)
    edge_pass1<<<EHB, B, 0, stream>>>(esrc, edst, qb, kb, menc, N_EDGES);
    edge_pass2<<<EHB, B, 0, stream>>>(esrc, edst, qb, kb, menc, denom, N_EDGES);
    edge_pass3<<<EHB, B, 0, stream>>>(esrc, edst, qb, kb, vb, menc, denom, r, N_EDGES);
    // h = h + agg @ Wo + bo
    gemm_kernel<float, float, false, true><<<G128, B, 0, stream>>>(
        r, Wo_l, bo + l * DIM, h, h, N_NODES, 128, 128);
    // FFN: h = h + relu(LN(h) @ Wf1 + bf1) @ Wf2 + bf2  (reference reuses g1/b1)
    ln_kernel<<<12500, B, 0, stream>>>(h, g1 + l * DIM, b1 + l * DIM, r, N_NODES);
    gemm_kernel<float, float, true, false><<<G256, B, 0, stream>>>(
        r, Wf1_l, bf1 + l * 2 * DIM, nullptr, ffnmid, N_NODES, 128, 256);
    gemm_kernel<float, float, false, true><<<G128, B, 0, stream>>>(
        ffnmid, Wf2_l, bf2 + l * DIM, h, h, N_NODES, 256, 128);
  }

  // output 0: mid = h (fp32, reference output dtype)
  copyf_kernel<<<(int)((ND + 255) / 256), B, 0, stream>>>(h, (float*)d_out, (int)ND);
  // output 1: LN(h, g_out, b_out) @ Wout + bout (fp32)
  ln_kernel<<<12500, B, 0, stream>>>(h, gout, bout_ln, r, N_NODES);
  gemm_kernel<float, float, false, false><<<G40, B, 0, stream>>>(
      r, Wout, bout, nullptr, ((float*)d_out) + ND, N_NODES, 128, 40);
}

// Round 4
// 3785.767 us; speedup vs baseline: 8.4147x; 8.4147x over previous
//
#include <hip/hip_runtime.h>
#include <hip/hip_bf16.h>

typedef __hip_bfloat16 bf16;

#define N_NODES 50000
#define N_EDGES 800000
#define DIM 128
#define NH 8
#define HDIM 16

__device__ __forceinline__ float toF(float x){ return x; }
__device__ __forceinline__ float toF(bf16 x){ return __bfloat162float(x); }
__device__ __forceinline__ void storeO(float* p, float v){ *p = v; }
__device__ __forceinline__ void storeO(bf16* p, float v){ *p = __float2bfloat16(v); }
__device__ __forceinline__ float bfu2f(unsigned short u){
  return __uint_as_float(((unsigned)u) << 16);
}

__global__ void fill_kernel(unsigned* __restrict__ p, unsigned val, int n){
  int i = blockIdx.x * blockDim.x + threadIdx.x;
  if (i < n) p[i] = val;
}

__global__ void copyf_kernel(const float* __restrict__ in, float* __restrict__ out, int n){
  int i = blockIdx.x * blockDim.x + threadIdx.x;
  if (i < n) out[i] = in[i];
}

// ---- CSR build (edges grouped by dst) ----
__global__ void hist_kernel(const int* __restrict__ dst, int* __restrict__ counts, int E){
  int e = blockIdx.x * blockDim.x + threadIdx.x;
  if (e < E) atomicAdd(counts + dst[e], 1);
}

// single-block exclusive scan of counts[0..n-1] -> rowptr[0..n]
__global__ __launch_bounds__(1024) void scan_kernel(const int* __restrict__ counts,
    int* __restrict__ rowptr, int n){
  __shared__ int buf[1024];
  int t = threadIdx.x;
  int running = 0;
  for (int base = 0; base < n; base += 1024){
    int x = (base + t < n) ? counts[base + t] : 0;
    buf[t] = x; __syncthreads();
    #pragma unroll
    for (int off = 1; off < 1024; off <<= 1){
      int val = (t >= off) ? buf[t - off] : 0;
      __syncthreads();
      buf[t] += val;
      __syncthreads();
    }
    if (base + t < n) rowptr[base + t] = running + buf[t] - x;
    running += buf[1023];
    __syncthreads();
  }
  if (t == 0) rowptr[n] = running;
}

__global__ void scatter_kernel(const int* __restrict__ src, const int* __restrict__ dst,
    const int* __restrict__ rowptr, int* __restrict__ cursor,
    int* __restrict__ srclist, int E){
  int e = blockIdx.x * blockDim.x + threadIdx.x;
  if (e >= E) return;
  int d = dst[e];
  int pos = rowptr[d] + atomicAdd(cursor + d, 1);
  srclist[pos] = src[e];
}

// ---- gather-style edge-softmax attention: one wave per dst node ----
// lane i holds dims {2i, 2i+1}; head of lane = i>>3 (lanes 8h..8h+7 cover head h)
__global__ __launch_bounds__(256) void attn_kernel(
    const int* __restrict__ rowptr, const int* __restrict__ srclist,
    const bf16* __restrict__ q, const bf16* __restrict__ k,
    const bf16* __restrict__ v, float* __restrict__ agg, int n){
  int d = blockIdx.x * 4 + (threadIdx.x >> 6);
  int lane = threadIdx.x & 63;
  if (d >= n) return;
  const ushort2* kp = (const ushort2*)(k + (size_t)d * DIM);
  ushort2 ku = kp[lane];
  float k0 = bfu2f(ku.x), k1 = bfu2f(ku.y);
  float m = -INFINITY, den = 0.f, acc0 = 0.f, acc1 = 0.f;
  int e1 = rowptr[d + 1];
  for (int e = rowptr[d]; e < e1; e++){
    int s = srclist[e];
    const ushort2* qp = (const ushort2*)(q + (size_t)s * DIM);
    ushort2 qu = qp[lane];
    float partial = bfu2f(qu.x) * k0 + bfu2f(qu.y) * k1;
    partial += __shfl_xor(partial, 1);
    partial += __shfl_xor(partial, 2);
    partial += __shfl_xor(partial, 4);
    float sc = partial * 0.25f;          // 1/sqrt(16)
    const ushort2* vp = (const ushort2*)(v + (size_t)s * DIM);
    ushort2 vu = vp[lane];
    float v0 = bfu2f(vu.x), v1 = bfu2f(vu.y);
    float mn = fmaxf(m, sc);
    float c = __expf(m - mn);
    float w = __expf(sc - mn);
    acc0 = acc0 * c + w * v0;
    acc1 = acc1 * c + w * v1;
    den = den * c + w;
    m = mn;
  }
  float inv = (den > 0.f) ? 1.f / den : 0.f;
  float2* ap = (float2*)(agg + (size_t)d * DIM);
  ap[lane] = make_float2(acc0 * inv, acc1 * inv);
}

// LayerNorm over rows of 128; one wave per row, 4 rows per block.
__global__ __launch_bounds__(256) void ln_kernel(const float* __restrict__ in,
    const float* __restrict__ g, const float* __restrict__ b,
    float* __restrict__ out, int n){
  int row = blockIdx.x * 4 + (threadIdx.x >> 6);
  int lane = threadIdx.x & 63;
  if (row >= n) return;
  const float* p = in + (size_t)row * DIM;
  float a0 = p[lane], a1 = p[lane + 64];
  float s = a0 + a1;
  #pragma unroll
  for (int o = 32; o > 0; o >>= 1) s += __shfl_xor(s, o);
  float mu = s * (1.f / 128.f);
  float d0 = a0 - mu, d1 = a1 - mu;
  float vs = d0 * d0 + d1 * d1;
  #pragma unroll
  for (int o = 32; o > 0; o >>= 1) vs += __shfl_xor(vs, o);
  float rs = rsqrtf(vs * (1.f / 128.f) + 1e-5f);
  out[(size_t)row * DIM + lane]      = d0 * rs * g[lane]      + b[lane];
  out[(size_t)row * DIM + lane + 64] = d1 * rs * g[lane + 64] + b[lane + 64];
}

// Generic tiled GEMM: out[n,M] = act(A[n,K] @ W[K,M] + bias) (+ resid)
template<typename AT, typename OT, bool RELU, bool RESID>
__global__ __launch_bounds__(256) void gemm_kernel(const AT* __restrict__ A,
    const float* __restrict__ W, const float* __restrict__ bias,
    const float* __restrict__ resid, OT* __restrict__ out,
    int n, int K, int M){
  __shared__ float As[32][65];
  __shared__ float Bs[32][65];
  int bm = blockIdx.x * 64;
  int bn = blockIdx.y * 64;
  int tid = threadIdx.x;
  int tx = tid & 15, ty = tid >> 4;
  float acc[4][4] = {{0.f}};
  for (int k0 = 0; k0 < K; k0 += 32){
    int ca = tid & 31, ra = tid >> 5;        // A tile: 64 rows x 32 k
    #pragma unroll
    for (int rr = 0; rr < 8; rr++){
      int r = ra + rr * 8;
      int gr = bm + r;
      float val = 0.f;
      if (gr < n) val = toF(A[(size_t)gr * K + k0 + ca]);
      As[ca][r] = val;
    }
    int cb = tid & 63, rb = tid >> 6;        // W tile: 32 k x 64 cols
    #pragma unroll
    for (int rr = 0; rr < 8; rr++){
      int r = rb + rr * 4;
      int gc = bn + cb;
      float val = 0.f;
      if (gc < M) val = W[(size_t)(k0 + r) * M + gc];
      Bs[r][cb] = val;
    }
    __syncthreads();
    #pragma unroll
    for (int kk = 0; kk < 32; kk++){
      float av[4], bv[4];
      #pragma unroll
      for (int i = 0; i < 4; i++) av[i] = As[kk][ty * 4 + i];
      #pragma unroll
      for (int j = 0; j < 4; j++) bv[j] = Bs[kk][tx * 4 + j];
      #pragma unroll
      for (int i = 0; i < 4; i++)
        #pragma unroll
        for (int j = 0; j < 4; j++) acc[i][j] += av[i] * bv[j];
    }
    __syncthreads();
  }
  #pragma unroll
  for (int i = 0; i < 4; i++){
    int gr = bm + ty * 4 + i;
    if (gr >= n) continue;
    #pragma unroll
    for (int j = 0; j < 4; j++){
      int gc = bn + tx * 4 + j;
      if (gc >= M) continue;
      float v = acc[i][j] + bias[gc];
      if (RELU) v = fmaxf(v, 0.f);
      if (RESID) v += resid[(size_t)gr * M + gc];
      storeO(out + (size_t)gr * M + gc, v);
    }
  }
}

extern "C" void kernel_launch(void* const* d_in, const int* in_sizes, int n_in,
                              void* d_out, int out_size, void* d_ws, size_t ws_size,
                              hipStream_t stream) {
  const float* x    = (const float*)d_in[0];
  const int*  esrc  = (const int*)d_in[1];
  const int*  edst  = (const int*)d_in[2];
  const float* Wi   = (const float*)d_in[3];
  const float* bi   = (const float*)d_in[4];
  const float* Wq   = (const float*)d_in[5];
  const float* bq   = (const float*)d_in[6];
  const float* Wk   = (const float*)d_in[7];
  const float* bk   = (const float*)d_in[8];
  const float* Wv   = (const float*)d_in[9];
  const float* bv   = (const float*)d_in[10];
  const float* Wo   = (const float*)d_in[11];
  const float* bo   = (const float*)d_in[12];
  const float* g1   = (const float*)d_in[13];
  const float* b1   = (const float*)d_in[14];
  const float* Wf1  = (const float*)d_in[15];
  const float* bf1  = (const float*)d_in[16];
  const float* Wf2  = (const float*)d_in[17];
  const float* bf2  = (const float*)d_in[18];
  const float* gout = (const float*)d_in[19];
  const float* bout_ln = (const float*)d_in[20];
  const float* Wout = (const float*)d_in[21];
  const float* bout = (const float*)d_in[22];

  // workspace: h(ND) | r(ND) | S(2*ND) fp32 = 102.4MB total (same proven budget)
  const size_t ND = (size_t)N_NODES * DIM;         // 6.4M
  float* ws = (float*)d_ws;
  float* h = ws;
  float* r = ws + ND;          // LN output / attention agg (reused)
  float* S = ws + 2 * ND;      // 2*ND floats scratch
  // overlays of S:
  bf16* qb = (bf16*)S;                 // ND bf16
  bf16* kb = qb + ND;                  // ND bf16
  bf16* vb = kb + ND;                  // ND bf16  (ends at S + 1.5*ND floats)
  bf16* ffnmid = qb;                   // [N,256] bf16 = ND*... overlays q/k/v (dead by FFN)
  // CSR lives in the tail (S + 1.5*ND .. S + 2*ND), never overwritten:
  int* rowptr  = (int*)(vb + ND);      // N+1 ints
  int* cnt     = rowptr + N_NODES + 1; // N ints (histogram, then scatter cursor)
  int* srclist = cnt + N_NODES;        // E ints

  dim3 B(256);
  dim3 G128(782, 2);
  dim3 G256(782, 4);
  dim3 G40(782, 1);
  const int EB = (N_EDGES + 255) / 256;

  // ---- build CSR once per call (edges constant across layers) ----
  fill_kernel<<<(N_NODES + 255) / 256, B, 0, stream>>>((unsigned*)cnt, 0u, N_NODES);
  hist_kernel<<<EB, B, 0, stream>>>(edst, cnt, N_EDGES);
  scan_kernel<<<1, 1024, 0, stream>>>(cnt, rowptr, N_NODES);
  fill_kernel<<<(N_NODES + 255) / 256, B, 0, stream>>>((unsigned*)cnt, 0u, N_NODES);
  scatter_kernel<<<EB, B, 0, stream>>>(esrc, edst, rowptr, cnt, srclist, N_EDGES);

  // h = relu(x @ Wi + bi)
  gemm_kernel<float, float, true, false><<<G128, B, 0, stream>>>(
      x, Wi, bi, nullptr, h, N_NODES, 256, 128);

  for (int l = 0; l < 5; l++){
    const float* Wq_l = Wq + (size_t)l * DIM * DIM;
    const float* Wk_l = Wk + (size_t)l * DIM * DIM;
    const float* Wv_l = Wv + (size_t)l * DIM * DIM;
    const float* Wo_l = Wo + (size_t)l * DIM * DIM;
    const float* Wf1_l = Wf1 + (size_t)l * DIM * 2 * DIM;
    const float* Wf2_l = Wf2 + (size_t)l * 2 * DIM * DIM;

    // r = LN(h)
    ln_kernel<<<12500, B, 0, stream>>>(h, g1 + l * DIM, b1 + l * DIM, r, N_NODES);
    // q/k/v projections (bf16 outputs)
    gemm_kernel<float, bf16, false, false><<<G128, B, 0, stream>>>(
        r, Wq_l, bq + l * DIM, nullptr, qb, N_NODES, 128, 128);
    gemm_kernel<float, bf16, false, false><<<G128, B, 0, stream>>>(
        r, Wk_l, bk + l * DIM, nullptr, kb, N_NODES, 128, 128);
    gemm_kernel<float, bf16, false, false><<<G128, B, 0, stream>>>(
        r, Wv_l, bv + l * DIM, nullptr, vb, N_NODES, 128, 128);
    // gather attention: agg -> r (no atomics)
    attn_kernel<<<12500, B, 0, stream>>>(rowptr, srclist, qb, kb, vb, r, N_NODES);
    // h = h + agg @ Wo + bo
    gemm_kernel<float, float, false, true><<<G128, B, 0, stream>>>(
        r, Wo_l, bo + l * DIM, h, h, N_NODES, 128, 128);
    // FFN: h = h + relu(LN(h) @ Wf1 + bf1) @ Wf2 + bf2  (reference reuses g1/b1)
    ln_kernel<<<12500, B, 0, stream>>>(h, g1 + l * DIM, b1 + l * DIM, r, N_NODES);
    gemm_kernel<float, bf16, true, false><<<G256, B, 0, stream>>>(
        r, Wf1_l, bf1 + l * 2 * DIM, nullptr, ffnmid, N_NODES, 128, 256);
    gemm_kernel<bf16, float, false, true><<<G128, B, 0, stream>>>(
        ffnmid, Wf2_l, bf2 + l * DIM, h, h, N_NODES, 256, 128);
  }

  // output 0: mid = h (fp32)
  copyf_kernel<<<(int)((ND + 255) / 256), B, 0, stream>>>(h, (float*)d_out, (int)ND);
  // output 1: LN(h, g_out, b_out) @ Wout + bout (fp32)
  ln_kernel<<<12500, B, 0, stream>>>(h, gout, bout_ln, r, N_NODES);
  gemm_kernel<float, float, false, false><<<G40, B, 0, stream>>>(
      r, Wout, bout, nullptr, ((float*)d_out) + ND, N_NODES, 128, 40);
}

// Round 5
// 1544.667 us; speedup vs baseline: 20.6233x; 2.4509x over previous
//
#include <hip/hip_runtime.h>
#include <hip/hip_bf16.h>

typedef __hip_bfloat16 bf16;
typedef __attribute__((ext_vector_type(8))) short bf16x8;
typedef __attribute__((ext_vector_type(4))) float f32x4;

#define N_NODES 50000
#define N_EDGES 800000
#define DIM 128
#define NH 8
#define HDIM 16
#define QKVW 384

__device__ __forceinline__ float toF(float x){ return x; }
__device__ __forceinline__ float toF(bf16 x){ return __bfloat162float(x); }
__device__ __forceinline__ void storeO(float* p, float v){ *p = v; }
__device__ __forceinline__ void storeO(bf16* p, float v){ *p = __float2bfloat16(v); }
__device__ __forceinline__ float bfu2f(unsigned short u){
  return __uint_as_float(((unsigned)u) << 16);
}

__global__ void fill_kernel(unsigned* __restrict__ p, unsigned val, int n){
  int i = blockIdx.x * blockDim.x + threadIdx.x;
  if (i < n) p[i] = val;
}

__global__ void copy4_kernel(const float4* __restrict__ in, float4* __restrict__ out, int n4){
  int i = blockIdx.x * blockDim.x + threadIdx.x;
  if (i < n4) out[i] = in[i];
}

__global__ void f2bf_kernel(const float* __restrict__ in, bf16* __restrict__ out, int n){
  int i = blockIdx.x * blockDim.x + threadIdx.x;
  if (i < n) out[i] = __float2bfloat16(in[i]);
}

// W[K][M] fp32 -> Wt[M][K] bf16
__global__ void transpose_bf16_kernel(const float* __restrict__ W, bf16* __restrict__ Wt,
    int K, int M){
  int idx = blockIdx.x * blockDim.x + threadIdx.x;
  if (idx >= K * M) return;
  int k = idx / M, m = idx - k * M;
  Wt[(size_t)m * K + k] = __float2bfloat16(W[idx]);
}

__global__ void pack_qkvbias_kernel(const float* __restrict__ bq, const float* __restrict__ bk,
    const float* __restrict__ bv, float* __restrict__ bqkv){
  int i = blockIdx.x * blockDim.x + threadIdx.x;
  if (i >= 5 * QKVW) return;
  int l = i / QKVW, j = i - l * QKVW;
  float v = (j < 128) ? bq[l * 128 + j] : (j < 256) ? bk[l * 128 + j - 128] : bv[l * 128 + j - 256];
  bqkv[i] = v;
}

// ---- CSR build (edges grouped by dst) ----
__global__ void hist_kernel(const int* __restrict__ dst, int* __restrict__ counts, int E){
  int e = blockIdx.x * blockDim.x + threadIdx.x;
  if (e < E) atomicAdd(counts + dst[e], 1);
}

__global__ __launch_bounds__(1024) void scan_kernel(const int* __restrict__ counts,
    int* __restrict__ rowptr, int n){
  __shared__ int buf[1024];
  int t = threadIdx.x;
  int running = 0;
  for (int base = 0; base < n; base += 1024){
    int x = (base + t < n) ? counts[base + t] : 0;
    buf[t] = x; __syncthreads();
    #pragma unroll
    for (int off = 1; off < 1024; off <<= 1){
      int val = (t >= off) ? buf[t - off] : 0;
      __syncthreads();
      buf[t] += val;
      __syncthreads();
    }
    if (base + t < n) rowptr[base + t] = running + buf[t] - x;
    running += buf[1023];
    __syncthreads();
  }
  if (t == 0) rowptr[n] = running;
}

__global__ void scatter_kernel(const int* __restrict__ src, const int* __restrict__ dst,
    const int* __restrict__ rowptr, int* __restrict__ cursor,
    int* __restrict__ srclist, int E){
  int e = blockIdx.x * blockDim.x + threadIdx.x;
  if (e >= E) return;
  int d = dst[e];
  int pos = rowptr[d] + atomicAdd(cursor + d, 1);
  srclist[pos] = src[e];
}

// ---- gather attention: one wave per dst; qkv packed [n][384] (q|k|v) ----
__global__ __launch_bounds__(256) void attn_kernel(
    const int* __restrict__ rowptr, const int* __restrict__ srclist,
    const bf16* __restrict__ qkv, bf16* __restrict__ agg, int n){
  int d = blockIdx.x * 4 + (threadIdx.x >> 6);
  int lane = threadIdx.x & 63;
  if (d >= n) return;
  const ushort2* kp = (const ushort2*)(qkv + (size_t)d * QKVW + 128);
  ushort2 ku = kp[lane];
  float k0 = bfu2f(ku.x), k1 = bfu2f(ku.y);
  float m = -INFINITY, den = 0.f, acc0 = 0.f, acc1 = 0.f;
  int e1 = rowptr[d + 1];
  for (int e = rowptr[d]; e < e1; e++){
    int s = srclist[e];
    const ushort2* qp = (const ushort2*)(qkv + (size_t)s * QKVW);
    ushort2 qu = qp[lane];
    float partial = bfu2f(qu.x) * k0 + bfu2f(qu.y) * k1;
    partial += __shfl_xor(partial, 1);
    partial += __shfl_xor(partial, 2);
    partial += __shfl_xor(partial, 4);
    float sc = partial * 0.25f;          // 1/sqrt(16)
    const ushort2* vp = (const ushort2*)(qkv + (size_t)s * QKVW + 256);
    ushort2 vu = vp[lane];
    float v0 = bfu2f(vu.x), v1 = bfu2f(vu.y);
    float mn = fmaxf(m, sc);
    float c = __expf(m - mn);
    float w = __expf(sc - mn);
    acc0 = acc0 * c + w * v0;
    acc1 = acc1 * c + w * v1;
    den = den * c + w;
    m = mn;
  }
  float inv = (den > 0.f) ? 1.f / den : 0.f;
  bf16* ap = agg + (size_t)d * DIM + lane * 2;
  ap[0] = __float2bfloat16(acc0 * inv);
  ap[1] = __float2bfloat16(acc1 * inv);
}

// LayerNorm rows of 128, fp32 in -> bf16 out; one wave per row.
__global__ __launch_bounds__(256) void ln_kernel(const float* __restrict__ in,
    const float* __restrict__ g, const float* __restrict__ b,
    bf16* __restrict__ out, int n){
  int row = blockIdx.x * 4 + (threadIdx.x >> 6);
  int lane = threadIdx.x & 63;
  if (row >= n) return;
  const float2* p = (const float2*)(in + (size_t)row * DIM);
  float2 a = p[lane];
  float s = a.x + a.y;
  #pragma unroll
  for (int o = 32; o > 0; o >>= 1) s += __shfl_xor(s, o);
  float mu = s * (1.f / 128.f);
  float d0 = a.x - mu, d1 = a.y - mu;
  float vs = d0 * d0 + d1 * d1;
  #pragma unroll
  for (int o = 32; o > 0; o >>= 1) vs += __shfl_xor(vs, o);
  float rs = rsqrtf(vs * (1.f / 128.f) + 1e-5f);
  float2 gg = ((const float2*)g)[lane];
  float2 bb = ((const float2*)b)[lane];
  bf16* op = out + (size_t)row * DIM + lane * 2;
  op[0] = __float2bfloat16(d0 * rs * gg.x + bb.x);
  op[1] = __float2bfloat16(d1 * rs * gg.y + bb.y);
}

// ---- MFMA bf16 GEMM: out[n,M] = act(A[n,K] @ Wt[M,K]^T + bias) (+resid) ----
// BM=64, BN=64, BK=128; 256 threads = 4 waves; wave w -> cols [16w,16w+16).
// mfma_f32_16x16x32_bf16: A-frag A[m=lane&15][k=quad*8+j]; C/D col=lane&15,row=quad*4+reg.
template<typename OT, bool RELU, bool RESID>
__global__ __launch_bounds__(256) void mfma_gemm(
    const bf16* __restrict__ A, const bf16* __restrict__ Wt,
    const float* __restrict__ bias, const float* __restrict__ resid,
    OT* __restrict__ out, int n, int K, int M){
  __shared__ short Ash[64][136];   // +8 bf16 pad per row
  __shared__ short Bsh[64][136];
  int tid = threadIdx.x;
  int wv = tid >> 6, lane = tid & 63;
  int l15 = lane & 15, quad = lane >> 4;
  int bm = blockIdx.y * 64;
  int bn = blockIdx.x * 64;
  f32x4 acc[4];
  #pragma unroll
  for (int i = 0; i < 4; i++) acc[i] = (f32x4){0.f, 0.f, 0.f, 0.f};

  for (int k0 = 0; k0 < K; k0 += 128){
    #pragma unroll
    for (int i = 0; i < 4; i++){
      int c = tid + i * 256;        // 0..1023
      int row = c >> 4;             // 0..63
      int off = (c & 15) * 8;       // bf16 offset 0..120
      int4 av = make_int4(0, 0, 0, 0);
      int gr = bm + row;
      if (gr < n) av = *(const int4*)(A + (size_t)gr * K + k0 + off);
      *(int4*)(&Ash[row][off]) = av;
      int4 bv = *(const int4*)(Wt + (size_t)(bn + row) * K + k0 + off);
      *(int4*)(&Bsh[row][off]) = bv;
    }
    __syncthreads();
    #pragma unroll
    for (int ks = 0; ks < 128; ks += 32){
      bf16x8 bfrag = *(const bf16x8*)(&Bsh[wv * 16 + l15][ks + quad * 8]);
      #pragma unroll
      for (int mi = 0; mi < 4; mi++){
        bf16x8 afrag = *(const bf16x8*)(&Ash[mi * 16 + l15][ks + quad * 8]);
        acc[mi] = __builtin_amdgcn_mfma_f32_16x16x32_bf16(afrag, bfrag, acc[mi], 0, 0, 0);
      }
    }
    __syncthreads();
  }

  int col = bn + wv * 16 + l15;
  float bval = bias[col];
  #pragma unroll
  for (int mi = 0; mi < 4; mi++){
    int row0 = bm + mi * 16 + quad * 4;
    #pragma unroll
    for (int rg = 0; rg < 4; rg++){
      int grow = row0 + rg;
      if (grow >= n) continue;
      float v = acc[mi][rg] + bval;
      if (RELU) v = fmaxf(v, 0.f);
      if (RESID) v += resid[(size_t)grow * M + col];
      storeO(out + (size_t)grow * M + col, v);
    }
  }
}

// small vector-ALU GEMM kept for the M=40 head
template<typename AT, typename OT, bool RELU, bool RESID>
__global__ __launch_bounds__(256) void gemm_kernel(const AT* __restrict__ A,
    const float* __restrict__ W, const float* __restrict__ bias,
    const float* __restrict__ resid, OT* __restrict__ out,
    int n, int K, int M){
  __shared__ float As[32][65];
  __shared__ float Bs[32][65];
  int bm = blockIdx.x * 64;
  int bn = blockIdx.y * 64;
  int tid = threadIdx.x;
  int tx = tid & 15, ty = tid >> 4;
  float acc[4][4] = {{0.f}};
  for (int k0 = 0; k0 < K; k0 += 32){
    int ca = tid & 31, ra = tid >> 5;
    #pragma unroll
    for (int rr = 0; rr < 8; rr++){
      int r = ra + rr * 8;
      int gr = bm + r;
      float val = 0.f;
      if (gr < n) val = toF(A[(size_t)gr * K + k0 + ca]);
      As[ca][r] = val;
    }
    int cb = tid & 63, rb = tid >> 6;
    #pragma unroll
    for (int rr = 0; rr < 8; rr++){
      int r = rb + rr * 4;
      int gc = bn + cb;
      float val = 0.f;
      if (gc < M) val = W[(size_t)(k0 + r) * M + gc];
      Bs[r][cb] = val;
    }
    __syncthreads();
    #pragma unroll
    for (int kk = 0; kk < 32; kk++){
      float av[4], bv[4];
      #pragma unroll
      for (int i = 0; i < 4; i++) av[i] = As[kk][ty * 4 + i];
      #pragma unroll
      for (int j = 0; j < 4; j++) bv[j] = Bs[kk][tx * 4 + j];
      #pragma unroll
      for (int i = 0; i < 4; i++)
        #pragma unroll
        for (int j = 0; j < 4; j++) acc[i][j] += av[i] * bv[j];
    }
    __syncthreads();
  }
  #pragma unroll
  for (int i = 0; i < 4; i++){
    int gr = bm + ty * 4 + i;
    if (gr >= n) continue;
    #pragma unroll
    for (int j = 0; j < 4; j++){
      int gc = bn + tx * 4 + j;
      if (gc >= M) continue;
      float v = acc[i][j] + bias[gc];
      if (RELU) v = fmaxf(v, 0.f);
      if (RESID) v += resid[(size_t)gr * M + gc];
      storeO(out + (size_t)gr * M + gc, v);
    }
  }
}

extern "C" void kernel_launch(void* const* d_in, const int* in_sizes, int n_in,
                              void* d_out, int out_size, void* d_ws, size_t ws_size,
                              hipStream_t stream) {
  const float* x    = (const float*)d_in[0];
  const int*  esrc  = (const int*)d_in[1];
  const int*  edst  = (const int*)d_in[2];
  const float* Wi   = (const float*)d_in[3];
  const float* bi   = (const float*)d_in[4];
  const float* Wq   = (const float*)d_in[5];
  const float* bq   = (const float*)d_in[6];
  const float* Wk   = (const float*)d_in[7];
  const float* bk   = (const float*)d_in[8];
  const float* Wv   = (const float*)d_in[9];
  const float* bv   = (const float*)d_in[10];
  const float* Wo   = (const float*)d_in[11];
  const float* bo   = (const float*)d_in[12];
  const float* g1   = (const float*)d_in[13];
  const float* b1   = (const float*)d_in[14];
  const float* Wf1  = (const float*)d_in[15];
  const float* bf1  = (const float*)d_in[16];
  const float* Wf2  = (const float*)d_in[17];
  const float* bf2  = (const float*)d_in[18];
  const float* gout = (const float*)d_in[19];
  const float* bout_ln = (const float*)d_in[20];
  const float* Wout = (const float*)d_in[21];
  const float* bout = (const float*)d_in[22];

  const size_t ND = (size_t)N_NODES * DIM;   // 6.4M
  float* ws = (float*)d_ws;
  // layout (float units):
  float* h   = ws;                           // ND f32
  bf16* r_bf = (bf16*)(ws + ND);             // ND bf16 (ND/2 floats)
  bf16* agg  = (bf16*)(ws + ND + ND / 2);    // ND bf16
  bf16* qkv  = (bf16*)(ws + 2 * ND);         // N*384 bf16 (9.6M floats)
  bf16* xb   = qkv;                          // overlay (dead before layer 0 qkv)
  bf16* mid  = qkv;                          // overlay [N,256] (qkv dead after attn)
  float* after_qkv = ws + 2 * ND + ((size_t)N_NODES * QKVW) / 2;
  // weights (bf16, transposed [M][K]):
  bf16* Wit    = (bf16*)after_qkv;                   // 256*128
  bf16* Wqkvt  = Wit + 256 * 128;                    // 5*384*128
  bf16* Wot    = Wqkvt + 5 * QKVW * 128;             // 5*128*128
  bf16* Wf1t   = Wot + 5 * 128 * 128;                // 5*256*128
  bf16* Wf2t   = Wf1t + 5 * 256 * 128;               // 5*128*256
  float* bqkv  = (float*)(Wf2t + 5 * 128 * 256);     // 5*384 f32
  int* rowptr  = (int*)(bqkv + 5 * QKVW);            // N+1
  int* cnt     = rowptr + N_NODES + 1;               // N
  int* srclist = cnt + N_NODES;                      // E

  dim3 B(256);
  const int EB = (N_EDGES + 255) / 256;
  const int NB = (N_NODES + 255) / 256;
  dim3 Gm128(2, 782);    // M=128 mfma grid
  dim3 Gm256(4, 782);
  dim3 Gm384(6, 782);

  // ---- prep: weight transpose/convert, x->bf16, bias pack, CSR ----
  f2bf_kernel<<<(int)((ND * 2 + 255) / 256), B, 0, stream>>>(x, xb, (int)(N_NODES * 256));
  transpose_bf16_kernel<<<(256 * 128 + 255) / 256, B, 0, stream>>>(Wi, Wit, 256, 128);
  for (int l = 0; l < 5; l++){
    transpose_bf16_kernel<<<(128 * 128 + 255) / 256, B, 0, stream>>>(
        Wq + (size_t)l * 128 * 128, Wqkvt + (size_t)l * QKVW * 128 + 0 * 128, 128, 128);
    transpose_bf16_kernel<<<(128 * 128 + 255) / 256, B, 0, stream>>>(
        Wk + (size_t)l * 128 * 128, Wqkvt + (size_t)l * QKVW * 128 + 128 * 128, 128, 128);
    transpose_bf16_kernel<<<(128 * 128 + 255) / 256, B, 0, stream>>>(
        Wv + (size_t)l * 128 * 128, Wqkvt + (size_t)l * QKVW * 128 + 256 * 128, 128, 128);
    transpose_bf16_kernel<<<(128 * 128 + 255) / 256, B, 0, stream>>>(
        Wo + (size_t)l * 128 * 128, Wot + (size_t)l * 128 * 128, 128, 128);
    transpose_bf16_kernel<<<(128 * 256 + 255) / 256, B, 0, stream>>>(
        Wf1 + (size_t)l * 128 * 256, Wf1t + (size_t)l * 256 * 128, 128, 256);
    transpose_bf16_kernel<<<(256 * 128 + 255) / 256, B, 0, stream>>>(
        Wf2 + (size_t)l * 256 * 128, Wf2t + (size_t)l * 128 * 256, 256, 128);
  }
  pack_qkvbias_kernel<<<(5 * QKVW + 255) / 256, B, 0, stream>>>(bq, bk, bv, bqkv);
  fill_kernel<<<NB, B, 0, stream>>>((unsigned*)cnt, 0u, N_NODES);
  hist_kernel<<<EB, B, 0, stream>>>(edst, cnt, N_EDGES);
  scan_kernel<<<1, 1024, 0, stream>>>(cnt, rowptr, N_NODES);
  fill_kernel<<<NB, B, 0, stream>>>((unsigned*)cnt, 0u, N_NODES);
  scatter_kernel<<<EB, B, 0, stream>>>(esrc, edst, rowptr, cnt, srclist, N_EDGES);

  // h = relu(x @ Wi + bi)   [K=256]
  mfma_gemm<float, true, false><<<Gm128, B, 0, stream>>>(
      xb, Wit, bi, nullptr, h, N_NODES, 256, 128);

  for (int l = 0; l < 5; l++){
    // r = LN(h) -> bf16
    ln_kernel<<<12500, B, 0, stream>>>(h, g1 + l * DIM, b1 + l * DIM, r_bf, N_NODES);
    // qkv = r @ [Wq|Wk|Wv] + [bq|bk|bv]
    mfma_gemm<bf16, false, false><<<Gm384, B, 0, stream>>>(
        r_bf, Wqkvt + (size_t)l * QKVW * 128, bqkv + l * QKVW, nullptr,
        qkv, N_NODES, 128, QKVW);
    // gather attention -> agg (bf16)
    attn_kernel<<<12500, B, 0, stream>>>(rowptr, srclist, qkv, agg, N_NODES);
    // h = h + agg @ Wo + bo
    mfma_gemm<float, false, true><<<Gm128, B, 0, stream>>>(
        agg, Wot + (size_t)l * 128 * 128, bo + l * DIM, h, h, N_NODES, 128, 128);
    // FFN
    ln_kernel<<<12500, B, 0, stream>>>(h, g1 + l * DIM, b1 + l * DIM, r_bf, N_NODES);
    mfma_gemm<bf16, true, false><<<Gm256, B, 0, stream>>>(
        r_bf, Wf1t + (size_t)l * 256 * 128, bf1 + l * 2 * DIM, nullptr,
        mid, N_NODES, 128, 256);
    mfma_gemm<float, false, true><<<Gm128, B, 0, stream>>>(
        mid, Wf2t + (size_t)l * 128 * 256, bf2 + l * DIM, h, h, N_NODES, 256, 128);
  }

  // output 0: mid = h (fp32)
  copy4_kernel<<<(int)((ND / 4 + 255) / 256), B, 0, stream>>>(
      (const float4*)h, (float4*)d_out, (int)(ND / 4));
  // output 1: LN(h) @ Wout + bout (fp32, M=40 head on vector-ALU GEMM)
  ln_kernel<<<12500, B, 0, stream>>>(h, gout, bout_ln, r_bf, N_NODES);
  gemm_kernel<bf16, float, false, false><<<dim3(782, 1), B, 0, stream>>>(
      r_bf, Wout, bout, nullptr, ((float*)d_out) + ND, N_NODES, 128, 40);
}

// Round 6
// 1251.317 us; speedup vs baseline: 25.4581x; 1.2344x over previous
//
#include <hip/hip_runtime.h>
#include <hip/hip_bf16.h>

typedef __hip_bfloat16 bf16;
typedef __attribute__((ext_vector_type(8))) short bf16x8;
typedef __attribute__((ext_vector_type(4))) float f32x4;

#define N_NODES 50000
#define N_EDGES 800000
#define DIM 128
#define NH 8
#define HDIM 16
#define QKVW 384

__device__ __forceinline__ float toF(bf16 x){ return __bfloat162float(x); }
__device__ __forceinline__ void storeO(float* p, float v){ *p = v; }
__device__ __forceinline__ void storeO(bf16* p, float v){ *p = __float2bfloat16(v); }
__device__ __forceinline__ float bfu2f(unsigned short u){
  return __uint_as_float(((unsigned)u) << 16);
}
__device__ __forceinline__ unsigned short f2bfbits(float f){
  bf16 t = __float2bfloat16(f);
  return *reinterpret_cast<unsigned short*>(&t);
}

__global__ void fill_kernel(unsigned* __restrict__ p, unsigned val, int n){
  int i = blockIdx.x * blockDim.x + threadIdx.x;
  if (i < n) p[i] = val;
}

// batched transpose+bf16: W[l][K][M] fp32 -> Wt[l][M][K] bf16, L layers
__global__ void prep_w_kernel(const float* __restrict__ W, bf16* __restrict__ Wt,
    int K, int M, int L){
  int idx = blockIdx.x * blockDim.x + threadIdx.x;
  int tot = L * K * M;
  if (idx >= tot) return;
  int l = idx / (K * M), r = idx - l * (K * M);
  int m = r / K, k = r - m * K;
  Wt[idx] = __float2bfloat16(W[(size_t)l * K * M + (size_t)k * M + m]);
}

// Wq|Wk|Wv [5][128][128] -> packed Wqkvt[5][384][128]
__global__ void prep_qkvw_kernel(const float* __restrict__ Wq, const float* __restrict__ Wk,
    const float* __restrict__ Wv, bf16* __restrict__ Wt){
  int idx = blockIdx.x * blockDim.x + threadIdx.x;
  if (idx >= 5 * QKVW * 128) return;
  int l = idx / (QKVW * 128), r = idx - l * (QKVW * 128);
  int m = r / 128, k = r - m * 128;
  const float* src = (m < 128) ? (Wq + (size_t)l * 16384 + (size_t)k * 128 + m)
                   : (m < 256) ? (Wk + (size_t)l * 16384 + (size_t)k * 128 + (m - 128))
                               : (Wv + (size_t)l * 16384 + (size_t)k * 128 + (m - 256));
  Wt[idx] = __float2bfloat16(*src);
}

__global__ void pack_qkvbias_kernel(const float* __restrict__ bq, const float* __restrict__ bk,
    const float* __restrict__ bv, float* __restrict__ bqkv){
  int i = blockIdx.x * blockDim.x + threadIdx.x;
  if (i >= 5 * QKVW) return;
  int l = i / QKVW, j = i - l * QKVW;
  float v = (j < 128) ? bq[l * 128 + j] : (j < 256) ? bk[l * 128 + j - 128] : bv[l * 128 + j - 256];
  bqkv[i] = v;
}

// ---- CSR build ----
__global__ void hist_kernel(const int* __restrict__ dst, int* __restrict__ counts, int E){
  int e = blockIdx.x * blockDim.x + threadIdx.x;
  if (e < E) atomicAdd(counts + dst[e], 1);
}

__global__ __launch_bounds__(1024) void scan_kernel(const int* __restrict__ counts,
    int* __restrict__ rowptr, int n){
  __shared__ int buf[1024];
  int t = threadIdx.x;
  int running = 0;
  for (int base = 0; base < n; base += 1024){
    int x = (base + t < n) ? counts[base + t] : 0;
    buf[t] = x; __syncthreads();
    #pragma unroll
    for (int off = 1; off < 1024; off <<= 1){
      int val = (t >= off) ? buf[t - off] : 0;
      __syncthreads();
      buf[t] += val;
      __syncthreads();
    }
    if (base + t < n) rowptr[base + t] = running + buf[t] - x;
    running += buf[1023];
    __syncthreads();
  }
  if (t == 0) rowptr[n] = running;
}

__global__ void scatter_kernel(const int* __restrict__ src, const int* __restrict__ dst,
    const int* __restrict__ rowptr, int* __restrict__ cursor,
    int* __restrict__ srclist, int E){
  int e = blockIdx.x * blockDim.x + threadIdx.x;
  if (e >= E) return;
  int d = dst[e];
  int pos = rowptr[d] + atomicAdd(cursor + d, 1);
  srclist[pos] = src[e];
}

// ---- gather attention, 4x unrolled edge pipeline; qkv packed [n][384] ----
#define ATTN_UPD(SC, VU) { \
  float mn = fmaxf(m, SC); \
  float c_ = __expf(m - mn); \
  float w_ = __expf(SC - mn); \
  acc0 = acc0 * c_ + w_ * bfu2f(VU.x); \
  acc1 = acc1 * c_ + w_ * bfu2f(VU.y); \
  den = den * c_ + w_; m = mn; }

__global__ __launch_bounds__(256) void attn_kernel(
    const int* __restrict__ rowptr, const int* __restrict__ srclist,
    const bf16* __restrict__ qkv, bf16* __restrict__ agg, int n){
  int d = blockIdx.x * 4 + (threadIdx.x >> 6);
  int lane = threadIdx.x & 63;
  if (d >= n) return;
  const ushort2* kp = (const ushort2*)(qkv + (size_t)d * QKVW + 128);
  ushort2 ku = kp[lane];
  float k0 = bfu2f(ku.x), k1 = bfu2f(ku.y);
  float m = -INFINITY, den = 0.f, acc0 = 0.f, acc1 = 0.f;
  int e = rowptr[d], e1 = rowptr[d + 1];
  for (; e + 4 <= e1; e += 4){
    int s0 = srclist[e], s1 = srclist[e + 1], s2 = srclist[e + 2], s3 = srclist[e + 3];
    ushort2 qu0 = ((const ushort2*)(qkv + (size_t)s0 * QKVW))[lane];
    ushort2 qu1 = ((const ushort2*)(qkv + (size_t)s1 * QKVW))[lane];
    ushort2 qu2 = ((const ushort2*)(qkv + (size_t)s2 * QKVW))[lane];
    ushort2 qu3 = ((const ushort2*)(qkv + (size_t)s3 * QKVW))[lane];
    ushort2 vu0 = ((const ushort2*)(qkv + (size_t)s0 * QKVW + 256))[lane];
    ushort2 vu1 = ((const ushort2*)(qkv + (size_t)s1 * QKVW + 256))[lane];
    ushort2 vu2 = ((const ushort2*)(qkv + (size_t)s2 * QKVW + 256))[lane];
    ushort2 vu3 = ((const ushort2*)(qkv + (size_t)s3 * QKVW + 256))[lane];
    float p0 = bfu2f(qu0.x) * k0 + bfu2f(qu0.y) * k1;
    float p1 = bfu2f(qu1.x) * k0 + bfu2f(qu1.y) * k1;
    float p2 = bfu2f(qu2.x) * k0 + bfu2f(qu2.y) * k1;
    float p3 = bfu2f(qu3.x) * k0 + bfu2f(qu3.y) * k1;
    p0 += __shfl_xor(p0, 1); p1 += __shfl_xor(p1, 1);
    p2 += __shfl_xor(p2, 1); p3 += __shfl_xor(p3, 1);
    p0 += __shfl_xor(p0, 2); p1 += __shfl_xor(p1, 2);
    p2 += __shfl_xor(p2, 2); p3 += __shfl_xor(p3, 2);
    p0 += __shfl_xor(p0, 4); p1 += __shfl_xor(p1, 4);
    p2 += __shfl_xor(p2, 4); p3 += __shfl_xor(p3, 4);
    float sc0 = p0 * 0.25f, sc1 = p1 * 0.25f, sc2 = p2 * 0.25f, sc3 = p3 * 0.25f;
    ATTN_UPD(sc0, vu0); ATTN_UPD(sc1, vu1); ATTN_UPD(sc2, vu2); ATTN_UPD(sc3, vu3);
  }
  for (; e < e1; e++){
    int s = srclist[e];
    ushort2 qu = ((const ushort2*)(qkv + (size_t)s * QKVW))[lane];
    ushort2 vu = ((const ushort2*)(qkv + (size_t)s * QKVW + 256))[lane];
    float p = bfu2f(qu.x) * k0 + bfu2f(qu.y) * k1;
    p += __shfl_xor(p, 1); p += __shfl_xor(p, 2); p += __shfl_xor(p, 4);
    float sc = p * 0.25f;
    ATTN_UPD(sc, vu);
  }
  float inv = (den > 0.f) ? 1.f / den : 0.f;
  bf16* ap = agg + (size_t)d * DIM + lane * 2;
  ap[0] = __float2bfloat16(acc0 * inv);
  ap[1] = __float2bfloat16(acc1 * inv);
}

// ---- MFMA GEMM v2: row-block owns A (LDS) once, loops over M col-tiles ----
// out[n,M] = act( LN?(A)[n,KT] @ Wt[M,KT]^T + bias ) (+resid); optional dual f32 out2.
// KT compile-time (128/256). FUSELN requires KT=128 (16-lane row reduction).
template<int KT, typename AT, bool FUSELN, bool RELU, bool RESID, typename OT>
__global__ __launch_bounds__(256) void mfma_gemm2(
    const AT* __restrict__ A, const float* __restrict__ lng, const float* __restrict__ lnb,
    const bf16* __restrict__ Wt, const float* __restrict__ bias,
    const float* __restrict__ resid, OT* __restrict__ out, float* __restrict__ out2,
    int n, int M){
  constexpr int CPR = KT / 8;               // 8-elem chunks per row
  __shared__ short Ash[64][KT + 8];
  __shared__ short Bsh[64][KT + 8];
  int tid = threadIdx.x;
  int wv = tid >> 6, lane = tid & 63;
  int l15 = lane & 15, quad = lane >> 4;
  int bm = blockIdx.x * 64;

  // stage A (convert to bf16; optional fused LayerNorm)
  #pragma unroll
  for (int i = 0; i < (64 * CPR) / 256; i++){
    int c = tid + i * 256;
    int row = c / CPR;
    int off = (c - row * CPR) * 8;
    int gr = bm + row;
    if constexpr (sizeof(AT) == 4) {      // fp32 A
      float va[8];
      if (gr < n){
        float4 f0 = *(const float4*)(A + (size_t)gr * KT + off);
        float4 f1 = *(const float4*)(A + (size_t)gr * KT + off + 4);
        va[0]=f0.x; va[1]=f0.y; va[2]=f0.z; va[3]=f0.w;
        va[4]=f1.x; va[5]=f1.y; va[6]=f1.z; va[7]=f1.w;
      } else {
        #pragma unroll
        for (int j = 0; j < 8; j++) va[j] = 0.f;
      }
      if constexpr (FUSELN){
        float s = va[0]+va[1]+va[2]+va[3]+va[4]+va[5]+va[6]+va[7];
        s += __shfl_xor(s, 1); s += __shfl_xor(s, 2);
        s += __shfl_xor(s, 4); s += __shfl_xor(s, 8);
        float mu = s * (1.f / 128.f);
        float vs = 0.f;
        #pragma unroll
        for (int j = 0; j < 8; j++){ float dd = va[j] - mu; vs += dd * dd; }
        vs += __shfl_xor(vs, 1); vs += __shfl_xor(vs, 2);
        vs += __shfl_xor(vs, 4); vs += __shfl_xor(vs, 8);
        float rs = rsqrtf(vs * (1.f / 128.f) + 1e-5f);
        float4 g0 = *(const float4*)(lng + off);
        float4 g1 = *(const float4*)(lng + off + 4);
        float4 b0 = *(const float4*)(lnb + off);
        float4 b1 = *(const float4*)(lnb + off + 4);
        va[0]=(va[0]-mu)*rs*g0.x+b0.x; va[1]=(va[1]-mu)*rs*g0.y+b0.y;
        va[2]=(va[2]-mu)*rs*g0.z+b0.z; va[3]=(va[3]-mu)*rs*g0.w+b0.w;
        va[4]=(va[4]-mu)*rs*g1.x+b1.x; va[5]=(va[5]-mu)*rs*g1.y+b1.y;
        va[6]=(va[6]-mu)*rs*g1.z+b1.z; va[7]=(va[7]-mu)*rs*g1.w+b1.w;
      }
      unsigned short tmp[8];
      #pragma unroll
      for (int j = 0; j < 8; j++) tmp[j] = f2bfbits(va[j]);
      *(int4*)(&Ash[row][off]) = *(const int4*)tmp;
    } else {                               // bf16 A: straight 16B copy
      int4 av = make_int4(0, 0, 0, 0);
      if (gr < n) av = *(const int4*)(A + (size_t)gr * KT + off);
      *(int4*)(&Ash[row][off]) = av;
    }
  }

  for (int bn = 0; bn < M; bn += 64){
    __syncthreads();    // prev compute done (and A staged) before overwriting Bsh
    #pragma unroll
    for (int i = 0; i < (64 * CPR) / 256; i++){
      int c = tid + i * 256;
      int row = c / CPR;
      int off = (c - row * CPR) * 8;
      int gc = bn + row;
      int4 bv = make_int4(0, 0, 0, 0);
      if (gc < M) bv = *(const int4*)(Wt + (size_t)gc * KT + off);
      *(int4*)(&Bsh[row][off]) = bv;
    }
    __syncthreads();
    f32x4 acc[4];
    #pragma unroll
    for (int i = 0; i < 4; i++) acc[i] = (f32x4){0.f, 0.f, 0.f, 0.f};
    #pragma unroll
    for (int ks = 0; ks < KT; ks += 32){
      bf16x8 bfrag = *(const bf16x8*)(&Bsh[wv * 16 + l15][ks + quad * 8]);
      #pragma unroll
      for (int mi = 0; mi < 4; mi++){
        bf16x8 afrag = *(const bf16x8*)(&Ash[mi * 16 + l15][ks + quad * 8]);
        acc[mi] = __builtin_amdgcn_mfma_f32_16x16x32_bf16(afrag, bfrag, acc[mi], 0, 0, 0);
      }
    }
    int col = bn + wv * 16 + l15;
    if (col < M){
      float bval = bias[col];
      #pragma unroll
      for (int mi = 0; mi < 4; mi++){
        int row0 = bm + mi * 16 + quad * 4;
        #pragma unroll
        for (int rg = 0; rg < 4; rg++){
          int grow = row0 + rg;
          if (grow >= n) continue;
          float v = acc[mi][rg] + bval;
          if (RELU) v = fmaxf(v, 0.f);
          if (RESID) v += resid[(size_t)grow * M + col];
          storeO(out + (size_t)grow * M + col, v);
          if (out2) out2[(size_t)grow * M + col] = v;
        }
      }
    }
  }
}

extern "C" void kernel_launch(void* const* d_in, const int* in_sizes, int n_in,
                              void* d_out, int out_size, void* d_ws, size_t ws_size,
                              hipStream_t stream) {
  const float* x    = (const float*)d_in[0];
  const int*  esrc  = (const int*)d_in[1];
  const int*  edst  = (const int*)d_in[2];
  const float* Wi   = (const float*)d_in[3];
  const float* bi   = (const float*)d_in[4];
  const float* Wq   = (const float*)d_in[5];
  const float* bq   = (const float*)d_in[6];
  const float* Wk   = (const float*)d_in[7];
  const float* bk   = (const float*)d_in[8];
  const float* Wv   = (const float*)d_in[9];
  const float* bv   = (const float*)d_in[10];
  const float* Wo   = (const float*)d_in[11];
  const float* bo   = (const float*)d_in[12];
  const float* g1   = (const float*)d_in[13];
  const float* b1   = (const float*)d_in[14];
  const float* Wf1  = (const float*)d_in[15];
  const float* bf1  = (const float*)d_in[16];
  const float* Wf2  = (const float*)d_in[17];
  const float* bf2  = (const float*)d_in[18];
  const float* gout = (const float*)d_in[19];
  const float* bout_ln = (const float*)d_in[20];
  const float* Wout = (const float*)d_in[21];
  const float* bout = (const float*)d_in[22];

  const size_t ND = (size_t)N_NODES * DIM;   // 6.4M
  float* ws = (float*)d_ws;
  float* h   = ws;                            // ND f32
  bf16* agg  = (bf16*)(ws + ND);              // ND bf16
  bf16* qkv  = (bf16*)(ws + ND + ND / 2);     // N*384 bf16
  bf16* mid  = qkv;                           // overlay [N,256] (qkv dead after attn)
  float* after_qkv = ws + ND + ND / 2 + ((size_t)N_NODES * QKVW) / 2;
  bf16* Wit    = (bf16*)after_qkv;                   // 128*256
  bf16* Wqkvt  = Wit + 128 * 256;                    // 5*384*128
  bf16* Wot    = Wqkvt + 5 * QKVW * 128;             // 5*128*128
  bf16* Wf1t   = Wot + 5 * 128 * 128;                // 5*256*128
  bf16* Wf2t   = Wf1t + 5 * 256 * 128;               // 5*128*256
  bf16* Woutt  = Wf2t + 5 * 128 * 256;               // 40*128
  float* bqkv  = (float*)(Woutt + 40 * 128);         // 5*384 f32
  int* rowptr  = (int*)(bqkv + 5 * QKVW);            // N+1
  int* cnt     = rowptr + N_NODES + 1;               // N
  int* srclist = cnt + N_NODES;                      // E

  dim3 B(256);
  const int EB = (N_EDGES + 255) / 256;
  const int NB = (N_NODES + 255) / 256;
  dim3 Grow(782);

  // ---- prep: weights -> bf16 transposed, bias pack, CSR ----
  prep_w_kernel<<<(1 * 256 * 128 + 255) / 256, B, 0, stream>>>(Wi, Wit, 256, 128, 1);
  prep_qkvw_kernel<<<(5 * QKVW * 128 + 255) / 256, B, 0, stream>>>(Wq, Wk, Wv, Wqkvt);
  prep_w_kernel<<<(5 * 128 * 128 + 255) / 256, B, 0, stream>>>(Wo, Wot, 128, 128, 5);
  prep_w_kernel<<<(5 * 128 * 256 + 255) / 256, B, 0, stream>>>(Wf1, Wf1t, 128, 256, 5);
  prep_w_kernel<<<(5 * 256 * 128 + 255) / 256, B, 0, stream>>>(Wf2, Wf2t, 256, 128, 5);
  prep_w_kernel<<<(1 * 128 * 40 + 255) / 256, B, 0, stream>>>(Wout, Woutt, 128, 40, 1);
  pack_qkvbias_kernel<<<(5 * QKVW + 255) / 256, B, 0, stream>>>(bq, bk, bv, bqkv);
  fill_kernel<<<NB, B, 0, stream>>>((unsigned*)cnt, 0u, N_NODES);
  hist_kernel<<<EB, B, 0, stream>>>(edst, cnt, N_EDGES);
  scan_kernel<<<1, 1024, 0, stream>>>(cnt, rowptr, N_NODES);
  fill_kernel<<<NB, B, 0, stream>>>((unsigned*)cnt, 0u, N_NODES);
  scatter_kernel<<<EB, B, 0, stream>>>(esrc, edst, rowptr, cnt, srclist, N_EDGES);

  // h = relu(x @ Wi + bi)   [x fp32 read in staging, K=256]
  mfma_gemm2<256, float, false, true, false, float><<<Grow, B, 0, stream>>>(
      x, nullptr, nullptr, Wit, bi, nullptr, h, nullptr, N_NODES, 128);

  for (int l = 0; l < 5; l++){
    // qkv = LN(h) @ [Wq|Wk|Wv] + [bq|bk|bv]   (LN fused in staging)
    mfma_gemm2<128, float, true, false, false, bf16><<<Grow, B, 0, stream>>>(
        h, g1 + l * DIM, b1 + l * DIM, Wqkvt + (size_t)l * QKVW * 128,
        bqkv + l * QKVW, nullptr, qkv, nullptr, N_NODES, QKVW);
    // gather attention -> agg
    attn_kernel<<<12500, B, 0, stream>>>(rowptr, srclist, qkv, agg, N_NODES);
    // h = h + agg @ Wo + bo
    mfma_gemm2<128, bf16, false, false, true, float><<<Grow, B, 0, stream>>>(
        agg, nullptr, nullptr, Wot + (size_t)l * 128 * 128, bo + l * DIM,
        h, h, nullptr, N_NODES, 128);
    // mid = relu(LN(h) @ Wf1 + bf1)   (LN fused; reference reuses g1/b1)
    mfma_gemm2<128, float, true, true, false, bf16><<<Grow, B, 0, stream>>>(
        h, g1 + l * DIM, b1 + l * DIM, Wf1t + (size_t)l * 256 * 128,
        bf1 + l * 2 * DIM, nullptr, mid, nullptr, N_NODES, 256);
    // h = h + mid @ Wf2 + bf2; last layer also writes d_out (mid output)
    float* out2 = (l == 4) ? (float*)d_out : nullptr;
    mfma_gemm2<256, bf16, false, false, true, float><<<Grow, B, 0, stream>>>(
        mid, nullptr, nullptr, Wf2t + (size_t)l * 128 * 256, bf2 + l * DIM,
        h, h, out2, N_NODES, 128);
  }

  // output 1: LN(h, g_out, b_out) @ Wout + bout  (LN fused, M=40)
  mfma_gemm2<128, float, true, false, false, float><<<Grow, B, 0, stream>>>(
      h, gout, bout_ln, Woutt, bout, nullptr, ((float*)d_out) + ND, nullptr, N_NODES, 40);
}